// Round 5
// baseline (1304.701 us; speedup 1.0000x reference)
//
#include <hip/hip_runtime.h>

// FNO2DTime on gfx950 — partial-DFT spectral conv, fp32 throughout.
//
// Key derivation (matches numpy/pocketfft irfftn semantics):
//   out[x,y,z] = (1/N) * Re{ sum_{kx,ky in K, kz in 0..7} c(kz) * Aout * e^{+i phi} }
//   c(0)=1 (c2r ignores Im of DC bin), c(kz>=1)=2 (Hermitian partner),
//   N = 128*128*20. Re taken once at the final (Y) inverse stage.

#define BB 4
#define CC 20
#define NX 128
#define NY 128
#define NZ 20
#define MM 8
#define NKX 16
#define NKY 16
#define NKZ 8
#define CH_STRIDE (NX * NY * NZ) /* 327680 */

// workspace offsets in floats
#define OFF_H    0u
#define OFF_T1   26214400u  /* [bc][x][kyi][z] cplx ; reused as u2 [bo][x][kyi][z] */
#define OFF_T2   32768000u  /* [bc][kxi][kyi][z] cplx ; reused as u1 */
#define OFF_A    33587200u  /* [b][i][kxi][kyi][kz] cplx */
#define OFF_AOUT 33914880u  /* [b][o][kxi][kyi][kz] cplx */
#define OFF_WXY  34242560u  /* [y][ki] cplx, e^{-2pi i y*kphys/128} */
#define OFF_WZ   34246656u  /* [z][kz] cplx, e^{-2pi i z*kz/20} */
// total 34,246,976 floats ~= 137 MB

__global__ void k_tables(float* __restrict__ Wxy, float* __restrict__ Wz) {
    int tid = blockIdx.x * blockDim.x + threadIdx.x;
    const double PI2 = 6.283185307179586476925286766559;
    if (tid < NX * NKX) {
        int y = tid >> 4, ki = tid & 15;
        int kphys = (ki < MM) ? ki : (NX - NKX + ki);   // 8..15 -> 120..127
        int p = (y * kphys) & (NX - 1);
        double ang = -PI2 * (double)p / (double)NX;
        Wxy[2 * tid]     = (float)cos(ang);
        Wxy[2 * tid + 1] = (float)sin(ang);
    } else if (tid < NX * NKX + NZ * NKZ) {
        int t = tid - NX * NKX;
        int z = t >> 3, kz = t & 7;
        int p = (z * kz) % NZ;
        double ang = -PI2 * (double)p / (double)NZ;
        Wz[2 * t]     = (float)cos(ang);
        Wz[2 * t + 1] = (float)sin(ang);
    }
}

// fc0 lift: h[b,c,x,y,t] = b0[c] + gx*w0[0,c] + gy*w0[1,c] + gt[t]*w0[2,c] + sum_k x[b,x,y,k]*w0[3+k,c]
__global__ __launch_bounds__(256) void k_fc0(const float* __restrict__ x,
                                             const float* __restrict__ w0,
                                             const float* __restrict__ b0,
                                             float* __restrict__ h) {
    int tid = blockIdx.x * blockDim.x + threadIdx.x;      // ((b*CC+c)*NX+xx)*NY+y
    if (tid >= BB * CC * NX * NY) return;
    int y = tid & 127;
    int r = tid >> 7;
    int xx = r & 127; r >>= 7;
    int c = r % CC;
    int b = r / CC;
    const float* xp = x + (((size_t)(b * NX + xx)) * NY + y) * NZ;
    float base = b0[c] + ((float)xx / 127.0f) * w0[0 * CC + c]
                       + ((float)y  / 127.0f) * w0[1 * CC + c];
#pragma unroll
    for (int k = 0; k < 20; k++) base = fmaf(xp[k], w0[(3 + k) * CC + c], base);
    float wt = w0[2 * CC + c];
    float* hp = h + (size_t)tid * NZ;
#pragma unroll
    for (int t = 0; t < 20; t++) hp[t] = base + ((float)(t + 1) / 20.0f) * wt;
}

// Y-DFT: t1[bc][x][kyi][z] = sum_y h[bc][x][y][z] * Wxy[y][kyi]
// block = (bc, xgroup of 4), 320 threads: (xl in 4) x (ki in 16) x (z0 in {0,4,8,12,16})
__global__ __launch_bounds__(320) void k_dft_y(const float* __restrict__ h,
                                               const float* __restrict__ Wxy,
                                               float* __restrict__ t1) {
    __shared__ __align__(16) float tile[4 * NY * NZ];   // 40 KB
    __shared__ __align__(16) float tw[NX * NKX * 2];    // 16 KB
    int bid = blockIdx.x;                // (b*CC+c)*32 + xg
    int bc = bid >> 5, xg = bid & 31;
    const float* hp = h + ((size_t)bc * NX + xg * 4) * (NY * NZ);
    for (int i = threadIdx.x; i < 4 * NY * NZ; i += 320) tile[i] = hp[i];
    for (int i = threadIdx.x; i < NX * NKX * 2; i += 320) tw[i] = Wxy[i];
    __syncthreads();
    int xl = threadIdx.x / 80;
    int rest = threadIdx.x % 80;
    int ki = rest / 5;
    int z0 = (rest % 5) * 4;
    const float* tp = tile + xl * (NY * NZ);
    float sr0 = 0, sr1 = 0, sr2 = 0, sr3 = 0, si0 = 0, si1 = 0, si2 = 0, si3 = 0;
    for (int y = 0; y < NY; y++) {
        const float4 v = *(const float4*)&tp[y * NZ + z0];
        const float2 w = *(const float2*)&tw[(y * NKX + ki) * 2];
        sr0 = fmaf(v.x, w.x, sr0); si0 = fmaf(v.x, w.y, si0);
        sr1 = fmaf(v.y, w.x, sr1); si1 = fmaf(v.y, w.y, si1);
        sr2 = fmaf(v.z, w.x, sr2); si2 = fmaf(v.z, w.y, si2);
        sr3 = fmaf(v.w, w.x, sr3); si3 = fmaf(v.w, w.y, si3);
    }
    int x = xg * 4 + xl;
    float* o = t1 + (((size_t)bc * NX + x) * NKY + ki) * (NZ * 2) + z0 * 2;
    float4 o0 = {sr0, si0, sr1, si1};
    float4 o1 = {sr2, si2, sr3, si3};
    *(float4*)&o[0] = o0;
    *(float4*)&o[4] = o1;
}

// X-DFT: t2[bc][kxi][kyi][z] = sum_x t1[bc][x][kyi][z] * Wxy[x][kxi]
// block = (bc, kyi), 320 threads: (ki in 16) x (z in 20)
__global__ __launch_bounds__(320) void k_dft_x(const float* __restrict__ t1,
                                               const float* __restrict__ Wxy,
                                               float* __restrict__ t2) {
    __shared__ __align__(16) float tile[NX * NZ * 2];   // 20.5 KB
    __shared__ __align__(16) float tw[NX * NKX * 2];    // 16 KB
    int bid = blockIdx.x;
    int bc = bid >> 4, kyi = bid & 15;
    const float* base = t1 + ((size_t)bc * NX * NKY * NZ + (size_t)kyi * NZ) * 2;
    for (int i = threadIdx.x; i < NX * NZ * 2; i += 320) {
        int xx = i / (NZ * 2), r2 = i % (NZ * 2);
        tile[i] = base[(size_t)xx * (NKY * NZ * 2) + r2];
    }
    for (int i = threadIdx.x; i < NX * NKX * 2; i += 320) tw[i] = Wxy[i];
    __syncthreads();
    int ki = threadIdx.x / NZ, z = threadIdx.x % NZ;
    float sr = 0.f, si = 0.f;
    for (int xx = 0; xx < NX; xx++) {
        const float2 a = *(const float2*)&tile[xx * (NZ * 2) + z * 2];
        const float2 w = *(const float2*)&tw[(xx * NKX + ki) * 2];
        sr += a.x * w.x - a.y * w.y;
        si += a.x * w.y + a.y * w.x;
    }
    float* o = t2 + ((((size_t)bc * NKX + ki) * NKY + kyi) * NZ + z) * 2;
    o[0] = sr; o[1] = si;
}

// Z-DFT: A[b][i][kxi][kyi][kz] = sum_z t2[..][z] * Wz[z][kz]
__global__ __launch_bounds__(256) void k_dft_z(const float* __restrict__ t2,
                                               const float* __restrict__ Wz,
                                               float* __restrict__ A) {
    int tid = blockIdx.x * blockDim.x + threadIdx.x;  // ((bc*16+kxi)*16+kyi)*8+kz
    if (tid >= BB * CC * NKX * NKY * NKZ) return;
    int kz = tid & 7;
    int rest = tid >> 3;
    const float* p = t2 + (size_t)rest * (NZ * 2);
    float sr = 0.f, si = 0.f;
#pragma unroll
    for (int z = 0; z < NZ; z++) {
        float2 a = *(const float2*)&p[2 * z];
        float2 w = *(const float2*)&Wz[(z * NKZ + kz) * 2];
        sr += a.x * w.x - a.y * w.y;
        si += a.x * w.y + a.y * w.x;
    }
    A[2 * tid] = sr; A[2 * tid + 1] = si;
}

// mode mix: Aout[b][o][m] = scale * sum_i A[b][i][m] * (wr + i wi)[l,q,i,o,mx,my,mz]
__global__ __launch_bounds__(256) void k_modemix(const float* __restrict__ A,
                                                 const float* __restrict__ wr,
                                                 const float* __restrict__ wi,
                                                 float* __restrict__ Aout, int layer) {
    int tid = blockIdx.x * blockDim.x + threadIdx.x;  // (((b*CC+o)*16+kxi)*16+kyi)*8+kz
    if (tid >= BB * CC * NKX * NKY * NKZ) return;
    int kz = tid & 7;
    int t = tid >> 3;
    int kyi = t & 15; t >>= 4;
    int kxi = t & 15; t >>= 4;
    int o = t % CC;
    int b = t / CC;
    int q = (kxi >= MM ? 1 : 0) + (kyi >= MM ? 2 : 0);
    int mx = kxi & 7, my = kyi & 7;
    size_t wbase = ((size_t)(layer * 4 + q) * (CC * CC) + o) * 512
                 + (size_t)(mx * 64 + my * 8 + kz);
    const float* Ab = A + ((size_t)b * CC * 2048 + (size_t)((kxi * NKY + kyi) * NKZ + kz)) * 2;
    float sr = 0.f, si = 0.f;
#pragma unroll
    for (int i = 0; i < CC; i++) {
        float ar = Ab[(size_t)i * 4096], ai = Ab[(size_t)i * 4096 + 1];
        float wrv = wr[wbase + (size_t)i * (CC * 512)];
        float wiv = wi[wbase + (size_t)i * (CC * 512)];
        sr += ar * wrv - ai * wiv;
        si += ar * wiv + ai * wrv;
    }
    float sc = (kz == 0 ? 1.0f : 2.0f) / 327680.0f;   // c(kz) / N
    Aout[2 * tid] = sr * sc; Aout[2 * tid + 1] = si * sc;
}

// inverse Z: u1[b][o][kxi][kyi][z] = sum_kz Aout * conj(Wz[z][kz])
__global__ __launch_bounds__(256) void k_invz(const float* __restrict__ Aout,
                                              const float* __restrict__ Wz,
                                              float* __restrict__ u1) {
    int tid = blockIdx.x * blockDim.x + threadIdx.x;  // rest*20+z
    if (tid >= BB * CC * NKX * NKY * NZ) return;
    int z = tid % NZ;
    int rest = tid / NZ;
    const float* p = Aout + (size_t)rest * (NKZ * 2);
    float sr = 0.f, si = 0.f;
#pragma unroll
    for (int kz = 0; kz < NKZ; kz++) {
        float2 a = *(const float2*)&p[2 * kz];
        float c = Wz[(z * NKZ + kz) * 2], s = -Wz[(z * NKZ + kz) * 2 + 1];
        sr += a.x * c - a.y * s;
        si += a.x * s + a.y * c;
    }
    u1[2 * tid] = sr; u1[2 * tid + 1] = si;
}

// inverse X: u2[bo][x][kyi][z] = sum_kxi u1[bo][kxi][kyi][z] * conj(Wxy[x][kxi])
__global__ __launch_bounds__(256) void k_invx(const float* __restrict__ u1,
                                              const float* __restrict__ Wxy,
                                              float* __restrict__ u2) {
    int tid = blockIdx.x * blockDim.x + threadIdx.x;  // ((bo*NX+x)*NKY+kyi)*NZ+z
    if (tid >= BB * CC * NX * NKY * NZ) return;
    int z = tid % NZ;
    int t = tid / NZ;
    int kyi = t & 15; t >>= 4;
    int x = t & 127;
    int bo = t >> 7;
    const float* p = u1 + ((size_t)bo * (NKX * NKY * NZ) + (size_t)(kyi * NZ + z)) * 2;
    float sr = 0.f, si = 0.f;
#pragma unroll
    for (int kxi = 0; kxi < NKX; kxi++) {
        float2 a = *(const float2*)&p[(size_t)kxi * (NKY * NZ * 2)];
        float c = Wxy[(x * NKX + kxi) * 2], s = -Wxy[(x * NKX + kxi) * 2 + 1];
        sr += a.x * c - a.y * s;
        si += a.x * s + a.y * c;
    }
    u2[2 * tid] = sr; u2[2 * tid + 1] = si;
}

// inverse Y + pointwise conv + bias + relu, IN PLACE on h.
// block = (b, x); each thread owns whole sites (all 20 channels) -> no hazard.
__global__ __launch_bounds__(256) void k_final(const float* __restrict__ u2,
                                               const float* __restrict__ Wxy,
                                               const float* __restrict__ cw,
                                               const float* __restrict__ cb,
                                               float* __restrict__ h) {
    __shared__ __align__(16) float su2[CC * NKY * NZ * 2];  // 51.2 KB
    int b = blockIdx.x >> 7, x = blockIdx.x & 127;
    for (int i = threadIdx.x; i < CC * NKY * NZ * 2; i += 256) {
        int o = i / (NKY * NZ * 2), r = i % (NKY * NZ * 2);
        su2[i] = u2[((size_t)(b * CC + o) * NX + x) * (NKY * NZ * 2) + r];
    }
    __syncthreads();
    for (int k = 0; k < 10; k++) {
        int sid = threadIdx.x + 256 * k;
        int y = sid / NZ, z = sid % NZ;
        float cy[NKY], sy[NKY];
#pragma unroll
        for (int kyi = 0; kyi < NKY; kyi++) {
            float2 w = *(const float2*)&Wxy[(y * NKX + kyi) * 2]; // L1-cached, 16 KB table
            cy[kyi] = w.x; sy[kyi] = w.y;
        }
        size_t hbase = (size_t)b * CC * CH_STRIDE + (size_t)x * (NY * NZ) + (size_t)(y * NZ + z);
        float hv[CC];
#pragma unroll
        for (int i = 0; i < CC; i++) hv[i] = h[hbase + (size_t)i * CH_STRIDE];
        for (int o = 0; o < CC; o++) {
            float acc = cb[o];
#pragma unroll
            for (int i = 0; i < CC; i++) acc = fmaf(cw[o * CC + i], hv[i], acc);
            const float* up = &su2[o * (NKY * NZ * 2) + z * 2];
            float sup = 0.f;
#pragma unroll
            for (int kyi = 0; kyi < NKY; kyi++) {
                float2 u = *(const float2*)&up[kyi * (NZ * 2)];
                // Re{(ur+i*ui) * e^{+i th}} with table = e^{-i th}=(c,s): = ur*c + ui*s
                sup = fmaf(u.x, cy[kyi], sup);
                sup = fmaf(u.y, sy[kyi], sup);
            }
            float v = acc + sup;
            h[hbase + (size_t)o * CH_STRIDE] = v > 0.f ? v : 0.f;
        }
    }
}

// head: out[b,x,y,t] = fc2(relu(fc1(h[b,:,x,y,t])))
__global__ __launch_bounds__(256) void k_head(const float* __restrict__ h,
                                              const float* __restrict__ w1,
                                              const float* __restrict__ b1,
                                              const float* __restrict__ w2,
                                              const float* __restrict__ b2,
                                              float* __restrict__ out) {
    int tid = blockIdx.x * blockDim.x + threadIdx.x;  // ((b*NX+x)*NY+y)*NZ+t
    if (tid >= BB * NX * NY * NZ) return;
    int t = tid % NZ;
    int r = tid / NZ;
    int y = r & 127; r >>= 7;
    int x = r & 127;
    int b = r >> 7;
    float hv[CC];
    size_t hbase = (size_t)b * CC * CH_STRIDE + (size_t)x * (NY * NZ) + (size_t)(y * NZ + t);
#pragma unroll
    for (int c = 0; c < CC; c++) hv[c] = h[hbase + (size_t)c * CH_STRIDE];
    float acc = b2[0];
    for (int j = 0; j < 128; j++) {
        float s = b1[j];
#pragma unroll
        for (int c = 0; c < CC; c++) s = fmaf(hv[c], w1[c * 128 + j], s);
        s = s > 0.f ? s : 0.f;
        acc = fmaf(s, w2[j], acc);
    }
    out[tid] = acc;
}

extern "C" void kernel_launch(void* const* d_in, const int* in_sizes, int n_in,
                              void* d_out, int out_size, void* d_ws, size_t ws_size,
                              hipStream_t stream) {
    const float* x       = (const float*)d_in[0];
    const float* spec_wr = (const float*)d_in[1];
    const float* spec_wi = (const float*)d_in[2];
    const float* conv_w  = (const float*)d_in[3];
    const float* conv_b  = (const float*)d_in[4];
    const float* fc0_w   = (const float*)d_in[5];
    const float* fc0_b   = (const float*)d_in[6];
    const float* fc1_w   = (const float*)d_in[7];
    const float* fc1_b   = (const float*)d_in[8];
    const float* fc2_w   = (const float*)d_in[9];
    const float* fc2_b   = (const float*)d_in[10];

    float* ws   = (float*)d_ws;
    float* h    = ws + OFF_H;
    float* t1   = ws + OFF_T1;
    float* t2   = ws + OFF_T2;
    float* A    = ws + OFF_A;
    float* Aout = ws + OFF_AOUT;
    float* Wxy  = ws + OFF_WXY;
    float* Wz   = ws + OFF_WZ;

    hipLaunchKernelGGL(k_tables, dim3(9), dim3(256), 0, stream, Wxy, Wz);
    hipLaunchKernelGGL(k_fc0, dim3(5120), dim3(256), 0, stream, x, fc0_w, fc0_b, h);
    for (int l = 0; l < 4; l++) {
        hipLaunchKernelGGL(k_dft_y, dim3(2560), dim3(320), 0, stream, h, Wxy, t1);
        hipLaunchKernelGGL(k_dft_x, dim3(1280), dim3(320), 0, stream, t1, Wxy, t2);
        hipLaunchKernelGGL(k_dft_z, dim3(640), dim3(256), 0, stream, t2, Wz, A);
        hipLaunchKernelGGL(k_modemix, dim3(640), dim3(256), 0, stream, A, spec_wr, spec_wi, Aout, l);
        hipLaunchKernelGGL(k_invz, dim3(1600), dim3(256), 0, stream, Aout, Wz, t2);
        hipLaunchKernelGGL(k_invx, dim3(12800), dim3(256), 0, stream, t2, Wxy, t1);
        hipLaunchKernelGGL(k_final, dim3(512), dim3(256), 0, stream, t1, Wxy,
                           conv_w + l * (CC * CC), conv_b + l * CC, h);
    }
    hipLaunchKernelGGL(k_head, dim3(5120), dim3(256), 0, stream,
                       h, fc1_w, fc1_b, fc2_w, fc2_b, (float*)d_out);
}

// Round 12
// 1190.294 us; speedup vs baseline: 1.0961x; 1.0961x over previous
//
#include <hip/hip_runtime.h>

// FNO2DTime on gfx950 — partial-DFT spectral conv, fp32 throughout.
//
// Key derivation (matches numpy/pocketfft irfftn semantics):
//   out[x,y,z] = (1/N) * Re{ sum_{kx,ky in K, kz in 0..7} c(kz) * Aout * e^{+i phi} }
//   c(0)=1 (c2r ignores Im of DC bin), c(kz>=1)=2 (Hermitian partner),
//   N = 128*128*20. Re taken once at the final (Y) inverse stage.
//
// R5: k_head rewritten — weights staged in LDS (uniform-address broadcast
// ds_read_b128), float4 j-chunks. Was 228 µs issue-bound on 2816 redundant
// per-thread global weight loads (VALUBusy 43%, hbm 3%).

#define BB 4
#define CC 20
#define NX 128
#define NY 128
#define NZ 20
#define MM 8
#define NKX 16
#define NKY 16
#define NKZ 8
#define CH_STRIDE (NX * NY * NZ) /* 327680 */

// workspace offsets in floats
#define OFF_H    0u
#define OFF_T1   26214400u  /* [bc][x][kyi][z] cplx ; reused as u2 [bo][x][kyi][z] */
#define OFF_T2   32768000u  /* [bc][kxi][kyi][z] cplx ; reused as u1 */
#define OFF_A    33587200u  /* [b][i][kxi][kyi][kz] cplx */
#define OFF_AOUT 33914880u  /* [b][o][kxi][kyi][kz] cplx */
#define OFF_WXY  34242560u  /* [y][ki] cplx, e^{-2pi i y*kphys/128} */
#define OFF_WZ   34246656u  /* [z][kz] cplx, e^{-2pi i z*kz/20} */
// total 34,246,976 floats ~= 137 MB

__global__ void k_tables(float* __restrict__ Wxy, float* __restrict__ Wz) {
    int tid = blockIdx.x * blockDim.x + threadIdx.x;
    const double PI2 = 6.283185307179586476925286766559;
    if (tid < NX * NKX) {
        int y = tid >> 4, ki = tid & 15;
        int kphys = (ki < MM) ? ki : (NX - NKX + ki);   // 8..15 -> 120..127
        int p = (y * kphys) & (NX - 1);
        double ang = -PI2 * (double)p / (double)NX;
        Wxy[2 * tid]     = (float)cos(ang);
        Wxy[2 * tid + 1] = (float)sin(ang);
    } else if (tid < NX * NKX + NZ * NKZ) {
        int t = tid - NX * NKX;
        int z = t >> 3, kz = t & 7;
        int p = (z * kz) % NZ;
        double ang = -PI2 * (double)p / (double)NZ;
        Wz[2 * t]     = (float)cos(ang);
        Wz[2 * t + 1] = (float)sin(ang);
    }
}

// fc0 lift: h[b,c,x,y,t] = b0[c] + gx*w0[0,c] + gy*w0[1,c] + gt[t]*w0[2,c] + sum_k x[b,x,y,k]*w0[3+k,c]
__global__ __launch_bounds__(256) void k_fc0(const float* __restrict__ x,
                                             const float* __restrict__ w0,
                                             const float* __restrict__ b0,
                                             float* __restrict__ h) {
    int tid = blockIdx.x * blockDim.x + threadIdx.x;      // ((b*CC+c)*NX+xx)*NY+y
    if (tid >= BB * CC * NX * NY) return;
    int y = tid & 127;
    int r = tid >> 7;
    int xx = r & 127; r >>= 7;
    int c = r % CC;
    int b = r / CC;
    const float* xp = x + (((size_t)(b * NX + xx)) * NY + y) * NZ;
    float base = b0[c] + ((float)xx / 127.0f) * w0[0 * CC + c]
                       + ((float)y  / 127.0f) * w0[1 * CC + c];
#pragma unroll
    for (int k = 0; k < 20; k++) base = fmaf(xp[k], w0[(3 + k) * CC + c], base);
    float wt = w0[2 * CC + c];
    float* hp = h + (size_t)tid * NZ;
#pragma unroll
    for (int t = 0; t < 20; t++) hp[t] = base + ((float)(t + 1) / 20.0f) * wt;
}

// Y-DFT: t1[bc][x][kyi][z] = sum_y h[bc][x][y][z] * Wxy[y][kyi]
// block = (bc, xgroup of 4), 320 threads: (xl in 4) x (ki in 16) x (z0 in {0,4,8,12,16})
__global__ __launch_bounds__(320) void k_dft_y(const float* __restrict__ h,
                                               const float* __restrict__ Wxy,
                                               float* __restrict__ t1) {
    __shared__ __align__(16) float tile[4 * NY * NZ];   // 40 KB
    __shared__ __align__(16) float tw[NX * NKX * 2];    // 16 KB
    int bid = blockIdx.x;                // (b*CC+c)*32 + xg
    int bc = bid >> 5, xg = bid & 31;
    const float* hp = h + ((size_t)bc * NX + xg * 4) * (NY * NZ);
    for (int i = threadIdx.x; i < 4 * NY * NZ; i += 320) tile[i] = hp[i];
    for (int i = threadIdx.x; i < NX * NKX * 2; i += 320) tw[i] = Wxy[i];
    __syncthreads();
    int xl = threadIdx.x / 80;
    int rest = threadIdx.x % 80;
    int ki = rest / 5;
    int z0 = (rest % 5) * 4;
    const float* tp = tile + xl * (NY * NZ);
    float sr0 = 0, sr1 = 0, sr2 = 0, sr3 = 0, si0 = 0, si1 = 0, si2 = 0, si3 = 0;
    for (int y = 0; y < NY; y++) {
        const float4 v = *(const float4*)&tp[y * NZ + z0];
        const float2 w = *(const float2*)&tw[(y * NKX + ki) * 2];
        sr0 = fmaf(v.x, w.x, sr0); si0 = fmaf(v.x, w.y, si0);
        sr1 = fmaf(v.y, w.x, sr1); si1 = fmaf(v.y, w.y, si1);
        sr2 = fmaf(v.z, w.x, sr2); si2 = fmaf(v.z, w.y, si2);
        sr3 = fmaf(v.w, w.x, sr3); si3 = fmaf(v.w, w.y, si3);
    }
    int x = xg * 4 + xl;
    float* o = t1 + (((size_t)bc * NX + x) * NKY + ki) * (NZ * 2) + z0 * 2;
    float4 o0 = {sr0, si0, sr1, si1};
    float4 o1 = {sr2, si2, sr3, si3};
    *(float4*)&o[0] = o0;
    *(float4*)&o[4] = o1;
}

// X-DFT: t2[bc][kxi][kyi][z] = sum_x t1[bc][x][kyi][z] * Wxy[x][kxi]
// block = (bc, kyi), 320 threads: (ki in 16) x (z in 20)
__global__ __launch_bounds__(320) void k_dft_x(const float* __restrict__ t1,
                                               const float* __restrict__ Wxy,
                                               float* __restrict__ t2) {
    __shared__ __align__(16) float tile[NX * NZ * 2];   // 20.5 KB
    __shared__ __align__(16) float tw[NX * NKX * 2];    // 16 KB
    int bid = blockIdx.x;
    int bc = bid >> 4, kyi = bid & 15;
    const float* base = t1 + ((size_t)bc * NX * NKY * NZ + (size_t)kyi * NZ) * 2;
    for (int i = threadIdx.x; i < NX * NZ * 2; i += 320) {
        int xx = i / (NZ * 2), r2 = i % (NZ * 2);
        tile[i] = base[(size_t)xx * (NKY * NZ * 2) + r2];
    }
    for (int i = threadIdx.x; i < NX * NKX * 2; i += 320) tw[i] = Wxy[i];
    __syncthreads();
    int ki = threadIdx.x / NZ, z = threadIdx.x % NZ;
    float sr = 0.f, si = 0.f;
    for (int xx = 0; xx < NX; xx++) {
        const float2 a = *(const float2*)&tile[xx * (NZ * 2) + z * 2];
        const float2 w = *(const float2*)&tw[(xx * NKX + ki) * 2];
        sr += a.x * w.x - a.y * w.y;
        si += a.x * w.y + a.y * w.x;
    }
    float* o = t2 + ((((size_t)bc * NKX + ki) * NKY + kyi) * NZ + z) * 2;
    o[0] = sr; o[1] = si;
}

// Z-DFT: A[b][i][kxi][kyi][kz] = sum_z t2[..][z] * Wz[z][kz]
__global__ __launch_bounds__(256) void k_dft_z(const float* __restrict__ t2,
                                               const float* __restrict__ Wz,
                                               float* __restrict__ A) {
    int tid = blockIdx.x * blockDim.x + threadIdx.x;  // ((bc*16+kxi)*16+kyi)*8+kz
    if (tid >= BB * CC * NKX * NKY * NKZ) return;
    int kz = tid & 7;
    int rest = tid >> 3;
    const float* p = t2 + (size_t)rest * (NZ * 2);
    float sr = 0.f, si = 0.f;
#pragma unroll
    for (int z = 0; z < NZ; z++) {
        float2 a = *(const float2*)&p[2 * z];
        float2 w = *(const float2*)&Wz[(z * NKZ + kz) * 2];
        sr += a.x * w.x - a.y * w.y;
        si += a.x * w.y + a.y * w.x;
    }
    A[2 * tid] = sr; A[2 * tid + 1] = si;
}

// mode mix: Aout[b][o][m] = scale * sum_i A[b][i][m] * (wr + i wi)[l,q,i,o,mx,my,mz]
__global__ __launch_bounds__(256) void k_modemix(const float* __restrict__ A,
                                                 const float* __restrict__ wr,
                                                 const float* __restrict__ wi,
                                                 float* __restrict__ Aout, int layer) {
    int tid = blockIdx.x * blockDim.x + threadIdx.x;  // (((b*CC+o)*16+kxi)*16+kyi)*8+kz
    if (tid >= BB * CC * NKX * NKY * NKZ) return;
    int kz = tid & 7;
    int t = tid >> 3;
    int kyi = t & 15; t >>= 4;
    int kxi = t & 15; t >>= 4;
    int o = t % CC;
    int b = t / CC;
    int q = (kxi >= MM ? 1 : 0) + (kyi >= MM ? 2 : 0);
    int mx = kxi & 7, my = kyi & 7;
    size_t wbase = ((size_t)(layer * 4 + q) * (CC * CC) + o) * 512
                 + (size_t)(mx * 64 + my * 8 + kz);
    const float* Ab = A + ((size_t)b * CC * 2048 + (size_t)((kxi * NKY + kyi) * NKZ + kz)) * 2;
    float sr = 0.f, si = 0.f;
#pragma unroll
    for (int i = 0; i < CC; i++) {
        float ar = Ab[(size_t)i * 4096], ai = Ab[(size_t)i * 4096 + 1];
        float wrv = wr[wbase + (size_t)i * (CC * 512)];
        float wiv = wi[wbase + (size_t)i * (CC * 512)];
        sr += ar * wrv - ai * wiv;
        si += ar * wiv + ai * wrv;
    }
    float sc = (kz == 0 ? 1.0f : 2.0f) / 327680.0f;   // c(kz) / N
    Aout[2 * tid] = sr * sc; Aout[2 * tid + 1] = si * sc;
}

// inverse Z: u1[b][o][kxi][kyi][z] = sum_kz Aout * conj(Wz[z][kz])
__global__ __launch_bounds__(256) void k_invz(const float* __restrict__ Aout,
                                              const float* __restrict__ Wz,
                                              float* __restrict__ u1) {
    int tid = blockIdx.x * blockDim.x + threadIdx.x;  // rest*20+z
    if (tid >= BB * CC * NKX * NKY * NZ) return;
    int z = tid % NZ;
    int rest = tid / NZ;
    const float* p = Aout + (size_t)rest * (NKZ * 2);
    float sr = 0.f, si = 0.f;
#pragma unroll
    for (int kz = 0; kz < NKZ; kz++) {
        float2 a = *(const float2*)&p[2 * kz];
        float c = Wz[(z * NKZ + kz) * 2], s = -Wz[(z * NKZ + kz) * 2 + 1];
        sr += a.x * c - a.y * s;
        si += a.x * s + a.y * c;
    }
    u1[2 * tid] = sr; u1[2 * tid + 1] = si;
}

// inverse X: u2[bo][x][kyi][z] = sum_kxi u1[bo][kxi][kyi][z] * conj(Wxy[x][kxi])
__global__ __launch_bounds__(256) void k_invx(const float* __restrict__ u1,
                                              const float* __restrict__ Wxy,
                                              float* __restrict__ u2) {
    int tid = blockIdx.x * blockDim.x + threadIdx.x;  // ((bo*NX+x)*NKY+kyi)*NZ+z
    if (tid >= BB * CC * NX * NKY * NZ) return;
    int z = tid % NZ;
    int t = tid / NZ;
    int kyi = t & 15; t >>= 4;
    int x = t & 127;
    int bo = t >> 7;
    const float* p = u1 + ((size_t)bo * (NKX * NKY * NZ) + (size_t)(kyi * NZ + z)) * 2;
    float sr = 0.f, si = 0.f;
#pragma unroll
    for (int kxi = 0; kxi < NKX; kxi++) {
        float2 a = *(const float2*)&p[(size_t)kxi * (NKY * NZ * 2)];
        float c = Wxy[(x * NKX + kxi) * 2], s = -Wxy[(x * NKX + kxi) * 2 + 1];
        sr += a.x * c - a.y * s;
        si += a.x * s + a.y * c;
    }
    u2[2 * tid] = sr; u2[2 * tid + 1] = si;
}

// inverse Y + pointwise conv + bias + relu, IN PLACE on h.
// block = (b, x); each thread owns whole sites (all 20 channels) -> no hazard.
__global__ __launch_bounds__(256) void k_final(const float* __restrict__ u2,
                                               const float* __restrict__ Wxy,
                                               const float* __restrict__ cw,
                                               const float* __restrict__ cb,
                                               float* __restrict__ h) {
    __shared__ __align__(16) float su2[CC * NKY * NZ * 2];  // 51.2 KB
    int b = blockIdx.x >> 7, x = blockIdx.x & 127;
    for (int i = threadIdx.x; i < CC * NKY * NZ * 2; i += 256) {
        int o = i / (NKY * NZ * 2), r = i % (NKY * NZ * 2);
        su2[i] = u2[((size_t)(b * CC + o) * NX + x) * (NKY * NZ * 2) + r];
    }
    __syncthreads();
    for (int k = 0; k < 10; k++) {
        int sid = threadIdx.x + 256 * k;
        int y = sid / NZ, z = sid % NZ;
        float cy[NKY], sy[NKY];
#pragma unroll
        for (int kyi = 0; kyi < NKY; kyi++) {
            float2 w = *(const float2*)&Wxy[(y * NKX + kyi) * 2]; // L1-cached, 16 KB table
            cy[kyi] = w.x; sy[kyi] = w.y;
        }
        size_t hbase = (size_t)b * CC * CH_STRIDE + (size_t)x * (NY * NZ) + (size_t)(y * NZ + z);
        float hv[CC];
#pragma unroll
        for (int i = 0; i < CC; i++) hv[i] = h[hbase + (size_t)i * CH_STRIDE];
        for (int o = 0; o < CC; o++) {
            float acc = cb[o];
#pragma unroll
            for (int i = 0; i < CC; i++) acc = fmaf(cw[o * CC + i], hv[i], acc);
            const float* up = &su2[o * (NKY * NZ * 2) + z * 2];
            float sup = 0.f;
#pragma unroll
            for (int kyi = 0; kyi < NKY; kyi++) {
                float2 u = *(const float2*)&up[kyi * (NZ * 2)];
                // Re{(ur+i*ui) * e^{+i th}} with table = e^{-i th}=(c,s): = ur*c + ui*s
                sup = fmaf(u.x, cy[kyi], sup);
                sup = fmaf(u.y, sy[kyi], sup);
            }
            float v = acc + sup;
            h[hbase + (size_t)o * CH_STRIDE] = v > 0.f ? v : 0.f;
        }
    }
}

// head: out[b,x,y,t] = fc2(relu(fc1(h[b,:,x,y,t])))
// R5: weights staged in LDS; j processed in float4 chunks; all weight reads are
// wave-uniform LDS broadcasts (free per m136). Summation order identical to ref
// kernel (b1 + c-ascending; acc j-ascending) -> bitwise-same result.
__global__ __launch_bounds__(256) void k_head(const float* __restrict__ h,
                                              const float* __restrict__ w1,
                                              const float* __restrict__ b1,
                                              const float* __restrict__ w2,
                                              const float* __restrict__ b2,
                                              float* __restrict__ out) {
    __shared__ __align__(16) float sw1[CC * 128];   // 10 KB
    __shared__ __align__(16) float sb1[128];
    __shared__ __align__(16) float sw2[128];
    for (int i = threadIdx.x; i < CC * 128; i += 256) sw1[i] = w1[i];
    if (threadIdx.x < 128) {
        sb1[threadIdx.x] = b1[threadIdx.x];
        sw2[threadIdx.x] = w2[threadIdx.x];
    }
    __syncthreads();
    int tid = blockIdx.x * blockDim.x + threadIdx.x;  // ((b*NX+x)*NY+y)*NZ+t
    if (tid >= BB * NX * NY * NZ) return;
    int t = tid % NZ;
    int r = tid / NZ;
    int y = r & 127; r >>= 7;
    int x = r & 127;
    int b = r >> 7;
    float hv[CC];
    size_t hbase = (size_t)b * CC * CH_STRIDE + (size_t)x * (NY * NZ) + (size_t)(y * NZ + t);
#pragma unroll
    for (int c = 0; c < CC; c++) hv[c] = h[hbase + (size_t)c * CH_STRIDE];
    float acc = b2[0];
    for (int jc = 0; jc < 32; jc++) {
        float4 s = *(const float4*)&sb1[jc * 4];
#pragma unroll
        for (int c = 0; c < CC; c++) {
            const float4 w = *(const float4*)&sw1[c * 128 + jc * 4];  // uniform -> LDS broadcast
            s.x = fmaf(hv[c], w.x, s.x);
            s.y = fmaf(hv[c], w.y, s.y);
            s.z = fmaf(hv[c], w.z, s.z);
            s.w = fmaf(hv[c], w.w, s.w);
        }
        const float4 v2 = *(const float4*)&sw2[jc * 4];
        acc = fmaf(fmaxf(s.x, 0.f), v2.x, acc);
        acc = fmaf(fmaxf(s.y, 0.f), v2.y, acc);
        acc = fmaf(fmaxf(s.z, 0.f), v2.z, acc);
        acc = fmaf(fmaxf(s.w, 0.f), v2.w, acc);
    }
    out[tid] = acc;
}

extern "C" void kernel_launch(void* const* d_in, const int* in_sizes, int n_in,
                              void* d_out, int out_size, void* d_ws, size_t ws_size,
                              hipStream_t stream) {
    const float* x       = (const float*)d_in[0];
    const float* spec_wr = (const float*)d_in[1];
    const float* spec_wi = (const float*)d_in[2];
    const float* conv_w  = (const float*)d_in[3];
    const float* conv_b  = (const float*)d_in[4];
    const float* fc0_w   = (const float*)d_in[5];
    const float* fc0_b   = (const float*)d_in[6];
    const float* fc1_w   = (const float*)d_in[7];
    const float* fc1_b   = (const float*)d_in[8];
    const float* fc2_w   = (const float*)d_in[9];
    const float* fc2_b   = (const float*)d_in[10];

    float* ws   = (float*)d_ws;
    float* h    = ws + OFF_H;
    float* t1   = ws + OFF_T1;
    float* t2   = ws + OFF_T2;
    float* A    = ws + OFF_A;
    float* Aout = ws + OFF_AOUT;
    float* Wxy  = ws + OFF_WXY;
    float* Wz   = ws + OFF_WZ;

    hipLaunchKernelGGL(k_tables, dim3(9), dim3(256), 0, stream, Wxy, Wz);
    hipLaunchKernelGGL(k_fc0, dim3(5120), dim3(256), 0, stream, x, fc0_w, fc0_b, h);
    for (int l = 0; l < 4; l++) {
        hipLaunchKernelGGL(k_dft_y, dim3(2560), dim3(320), 0, stream, h, Wxy, t1);
        hipLaunchKernelGGL(k_dft_x, dim3(1280), dim3(320), 0, stream, t1, Wxy, t2);
        hipLaunchKernelGGL(k_dft_z, dim3(640), dim3(256), 0, stream, t2, Wz, A);
        hipLaunchKernelGGL(k_modemix, dim3(640), dim3(256), 0, stream, A, spec_wr, spec_wi, Aout, l);
        hipLaunchKernelGGL(k_invz, dim3(1600), dim3(256), 0, stream, Aout, Wz, t2);
        hipLaunchKernelGGL(k_invx, dim3(12800), dim3(256), 0, stream, t2, Wxy, t1);
        hipLaunchKernelGGL(k_final, dim3(512), dim3(256), 0, stream, t1, Wxy,
                           conv_w + l * (CC * CC), conv_b + l * CC, h);
    }
    hipLaunchKernelGGL(k_head, dim3(5120), dim3(256), 0, stream,
                       h, fc1_w, fc1_b, fc2_w, fc2_b, (float*)d_out);
}

// Round 15
// 1187.933 us; speedup vs baseline: 1.0983x; 1.0020x over previous
//
#include <hip/hip_runtime.h>

// FNO2DTime on gfx950 — partial-DFT spectral conv, fp32 throughout.
//
// Key derivation (matches numpy/pocketfft irfftn semantics):
//   out[x,y,z] = (1/N) * Re{ sum_{kx,ky in K, kz in 0..7} c(kz) * Aout * e^{+i phi} }
//   c(0)=1 (c2r ignores Im of DC bin), c(kz>=1)=2 (Hermitian partner),
//   N = 128*128*20. Re taken once at the final (Y) inverse stage.
//
// R5:  k_head weights staged in LDS (228 -> 124 us; VALUBusy 43->84%).
// R12: k_head 4 sites/thread (amortize 640 uniform ds_read_b128 over 4 outputs;
//      was LDS-issue/lgkmcnt-stall bound, FMA floor ~43 us). k_final split into
//      y-halves: 512 blocks (2 waves/SIMD, grid-starved) -> 1024 (3/SIMD).

#define BB 4
#define CC 20
#define NX 128
#define NY 128
#define NZ 20
#define MM 8
#define NKX 16
#define NKY 16
#define NKZ 8
#define CH_STRIDE (NX * NY * NZ) /* 327680 */

// workspace offsets in floats
#define OFF_H    0u
#define OFF_T1   26214400u  /* [bc][x][kyi][z] cplx ; reused as u2 [bo][x][kyi][z] */
#define OFF_T2   32768000u  /* [bc][kxi][kyi][z] cplx ; reused as u1 */
#define OFF_A    33587200u  /* [b][i][kxi][kyi][kz] cplx */
#define OFF_AOUT 33914880u  /* [b][o][kxi][kyi][kz] cplx */
#define OFF_WXY  34242560u  /* [y][ki] cplx, e^{-2pi i y*kphys/128} */
#define OFF_WZ   34246656u  /* [z][kz] cplx, e^{-2pi i z*kz/20} */
// total 34,246,976 floats ~= 137 MB

__global__ void k_tables(float* __restrict__ Wxy, float* __restrict__ Wz) {
    int tid = blockIdx.x * blockDim.x + threadIdx.x;
    const double PI2 = 6.283185307179586476925286766559;
    if (tid < NX * NKX) {
        int y = tid >> 4, ki = tid & 15;
        int kphys = (ki < MM) ? ki : (NX - NKX + ki);   // 8..15 -> 120..127
        int p = (y * kphys) & (NX - 1);
        double ang = -PI2 * (double)p / (double)NX;
        Wxy[2 * tid]     = (float)cos(ang);
        Wxy[2 * tid + 1] = (float)sin(ang);
    } else if (tid < NX * NKX + NZ * NKZ) {
        int t = tid - NX * NKX;
        int z = t >> 3, kz = t & 7;
        int p = (z * kz) % NZ;
        double ang = -PI2 * (double)p / (double)NZ;
        Wz[2 * t]     = (float)cos(ang);
        Wz[2 * t + 1] = (float)sin(ang);
    }
}

// fc0 lift: h[b,c,x,y,t] = b0[c] + gx*w0[0,c] + gy*w0[1,c] + gt[t]*w0[2,c] + sum_k x[b,x,y,k]*w0[3+k,c]
__global__ __launch_bounds__(256) void k_fc0(const float* __restrict__ x,
                                             const float* __restrict__ w0,
                                             const float* __restrict__ b0,
                                             float* __restrict__ h) {
    int tid = blockIdx.x * blockDim.x + threadIdx.x;      // ((b*CC+c)*NX+xx)*NY+y
    if (tid >= BB * CC * NX * NY) return;
    int y = tid & 127;
    int r = tid >> 7;
    int xx = r & 127; r >>= 7;
    int c = r % CC;
    int b = r / CC;
    const float* xp = x + (((size_t)(b * NX + xx)) * NY + y) * NZ;
    float base = b0[c] + ((float)xx / 127.0f) * w0[0 * CC + c]
                       + ((float)y  / 127.0f) * w0[1 * CC + c];
#pragma unroll
    for (int k = 0; k < 20; k++) base = fmaf(xp[k], w0[(3 + k) * CC + c], base);
    float wt = w0[2 * CC + c];
    float* hp = h + (size_t)tid * NZ;
#pragma unroll
    for (int t = 0; t < 20; t++) hp[t] = base + ((float)(t + 1) / 20.0f) * wt;
}

// Y-DFT: t1[bc][x][kyi][z] = sum_y h[bc][x][y][z] * Wxy[y][kyi]
// block = (bc, xgroup of 4), 320 threads: (xl in 4) x (ki in 16) x (z0 in {0,4,8,12,16})
__global__ __launch_bounds__(320) void k_dft_y(const float* __restrict__ h,
                                               const float* __restrict__ Wxy,
                                               float* __restrict__ t1) {
    __shared__ __align__(16) float tile[4 * NY * NZ];   // 40 KB
    __shared__ __align__(16) float tw[NX * NKX * 2];    // 16 KB
    int bid = blockIdx.x;                // (b*CC+c)*32 + xg
    int bc = bid >> 5, xg = bid & 31;
    const float* hp = h + ((size_t)bc * NX + xg * 4) * (NY * NZ);
    for (int i = threadIdx.x; i < 4 * NY * NZ; i += 320) tile[i] = hp[i];
    for (int i = threadIdx.x; i < NX * NKX * 2; i += 320) tw[i] = Wxy[i];
    __syncthreads();
    int xl = threadIdx.x / 80;
    int rest = threadIdx.x % 80;
    int ki = rest / 5;
    int z0 = (rest % 5) * 4;
    const float* tp = tile + xl * (NY * NZ);
    float sr0 = 0, sr1 = 0, sr2 = 0, sr3 = 0, si0 = 0, si1 = 0, si2 = 0, si3 = 0;
    for (int y = 0; y < NY; y++) {
        const float4 v = *(const float4*)&tp[y * NZ + z0];
        const float2 w = *(const float2*)&tw[(y * NKX + ki) * 2];
        sr0 = fmaf(v.x, w.x, sr0); si0 = fmaf(v.x, w.y, si0);
        sr1 = fmaf(v.y, w.x, sr1); si1 = fmaf(v.y, w.y, si1);
        sr2 = fmaf(v.z, w.x, sr2); si2 = fmaf(v.z, w.y, si2);
        sr3 = fmaf(v.w, w.x, sr3); si3 = fmaf(v.w, w.y, si3);
    }
    int x = xg * 4 + xl;
    float* o = t1 + (((size_t)bc * NX + x) * NKY + ki) * (NZ * 2) + z0 * 2;
    float4 o0 = {sr0, si0, sr1, si1};
    float4 o1 = {sr2, si2, sr3, si3};
    *(float4*)&o[0] = o0;
    *(float4*)&o[4] = o1;
}

// X-DFT: t2[bc][kxi][kyi][z] = sum_x t1[bc][x][kyi][z] * Wxy[x][kxi]
// block = (bc, kyi), 320 threads: (ki in 16) x (z in 20)
__global__ __launch_bounds__(320) void k_dft_x(const float* __restrict__ t1,
                                               const float* __restrict__ Wxy,
                                               float* __restrict__ t2) {
    __shared__ __align__(16) float tile[NX * NZ * 2];   // 20.5 KB
    __shared__ __align__(16) float tw[NX * NKX * 2];    // 16 KB
    int bid = blockIdx.x;
    int bc = bid >> 4, kyi = bid & 15;
    const float* base = t1 + ((size_t)bc * NX * NKY * NZ + (size_t)kyi * NZ) * 2;
    for (int i = threadIdx.x; i < NX * NZ * 2; i += 320) {
        int xx = i / (NZ * 2), r2 = i % (NZ * 2);
        tile[i] = base[(size_t)xx * (NKY * NZ * 2) + r2];
    }
    for (int i = threadIdx.x; i < NX * NKX * 2; i += 320) tw[i] = Wxy[i];
    __syncthreads();
    int ki = threadIdx.x / NZ, z = threadIdx.x % NZ;
    float sr = 0.f, si = 0.f;
    for (int xx = 0; xx < NX; xx++) {
        const float2 a = *(const float2*)&tile[xx * (NZ * 2) + z * 2];
        const float2 w = *(const float2*)&tw[(xx * NKX + ki) * 2];
        sr += a.x * w.x - a.y * w.y;
        si += a.x * w.y + a.y * w.x;
    }
    float* o = t2 + ((((size_t)bc * NKX + ki) * NKY + kyi) * NZ + z) * 2;
    o[0] = sr; o[1] = si;
}

// Z-DFT: A[b][i][kxi][kyi][kz] = sum_z t2[..][z] * Wz[z][kz]
__global__ __launch_bounds__(256) void k_dft_z(const float* __restrict__ t2,
                                               const float* __restrict__ Wz,
                                               float* __restrict__ A) {
    int tid = blockIdx.x * blockDim.x + threadIdx.x;  // ((bc*16+kxi)*16+kyi)*8+kz
    if (tid >= BB * CC * NKX * NKY * NKZ) return;
    int kz = tid & 7;
    int rest = tid >> 3;
    const float* p = t2 + (size_t)rest * (NZ * 2);
    float sr = 0.f, si = 0.f;
#pragma unroll
    for (int z = 0; z < NZ; z++) {
        float2 a = *(const float2*)&p[2 * z];
        float2 w = *(const float2*)&Wz[(z * NKZ + kz) * 2];
        sr += a.x * w.x - a.y * w.y;
        si += a.x * w.y + a.y * w.x;
    }
    A[2 * tid] = sr; A[2 * tid + 1] = si;
}

// mode mix: Aout[b][o][m] = scale * sum_i A[b][i][m] * (wr + i wi)[l,q,i,o,mx,my,mz]
__global__ __launch_bounds__(256) void k_modemix(const float* __restrict__ A,
                                                 const float* __restrict__ wr,
                                                 const float* __restrict__ wi,
                                                 float* __restrict__ Aout, int layer) {
    int tid = blockIdx.x * blockDim.x + threadIdx.x;  // (((b*CC+o)*16+kxi)*16+kyi)*8+kz
    if (tid >= BB * CC * NKX * NKY * NKZ) return;
    int kz = tid & 7;
    int t = tid >> 3;
    int kyi = t & 15; t >>= 4;
    int kxi = t & 15; t >>= 4;
    int o = t % CC;
    int b = t / CC;
    int q = (kxi >= MM ? 1 : 0) + (kyi >= MM ? 2 : 0);
    int mx = kxi & 7, my = kyi & 7;
    size_t wbase = ((size_t)(layer * 4 + q) * (CC * CC) + o) * 512
                 + (size_t)(mx * 64 + my * 8 + kz);
    const float* Ab = A + ((size_t)b * CC * 2048 + (size_t)((kxi * NKY + kyi) * NKZ + kz)) * 2;
    float sr = 0.f, si = 0.f;
#pragma unroll
    for (int i = 0; i < CC; i++) {
        float ar = Ab[(size_t)i * 4096], ai = Ab[(size_t)i * 4096 + 1];
        float wrv = wr[wbase + (size_t)i * (CC * 512)];
        float wiv = wi[wbase + (size_t)i * (CC * 512)];
        sr += ar * wrv - ai * wiv;
        si += ar * wiv + ai * wrv;
    }
    float sc = (kz == 0 ? 1.0f : 2.0f) / 327680.0f;   // c(kz) / N
    Aout[2 * tid] = sr * sc; Aout[2 * tid + 1] = si * sc;
}

// inverse Z: u1[b][o][kxi][kyi][z] = sum_kz Aout * conj(Wz[z][kz])
__global__ __launch_bounds__(256) void k_invz(const float* __restrict__ Aout,
                                              const float* __restrict__ Wz,
                                              float* __restrict__ u1) {
    int tid = blockIdx.x * blockDim.x + threadIdx.x;  // rest*20+z
    if (tid >= BB * CC * NKX * NKY * NZ) return;
    int z = tid % NZ;
    int rest = tid / NZ;
    const float* p = Aout + (size_t)rest * (NKZ * 2);
    float sr = 0.f, si = 0.f;
#pragma unroll
    for (int kz = 0; kz < NKZ; kz++) {
        float2 a = *(const float2*)&p[2 * kz];
        float c = Wz[(z * NKZ + kz) * 2], s = -Wz[(z * NKZ + kz) * 2 + 1];
        sr += a.x * c - a.y * s;
        si += a.x * s + a.y * c;
    }
    u1[2 * tid] = sr; u1[2 * tid + 1] = si;
}

// inverse X: u2[bo][x][kyi][z] = sum_kxi u1[bo][kxi][kyi][z] * conj(Wxy[x][kxi])
__global__ __launch_bounds__(256) void k_invx(const float* __restrict__ u1,
                                              const float* __restrict__ Wxy,
                                              float* __restrict__ u2) {
    int tid = blockIdx.x * blockDim.x + threadIdx.x;  // ((bo*NX+x)*NKY+kyi)*NZ+z
    if (tid >= BB * CC * NX * NKY * NZ) return;
    int z = tid % NZ;
    int t = tid / NZ;
    int kyi = t & 15; t >>= 4;
    int x = t & 127;
    int bo = t >> 7;
    const float* p = u1 + ((size_t)bo * (NKX * NKY * NZ) + (size_t)(kyi * NZ + z)) * 2;
    float sr = 0.f, si = 0.f;
#pragma unroll
    for (int kxi = 0; kxi < NKX; kxi++) {
        float2 a = *(const float2*)&p[(size_t)kxi * (NKY * NZ * 2)];
        float c = Wxy[(x * NKX + kxi) * 2], s = -Wxy[(x * NKX + kxi) * 2 + 1];
        sr += a.x * c - a.y * s;
        si += a.x * s + a.y * c;
    }
    u2[2 * tid] = sr; u2[2 * tid + 1] = si;
}

// inverse Y + pointwise conv + bias + relu, IN PLACE on h.
// R12: block = (b, x, y-half): 1024 blocks, 5 site-iterations each (was 512 x 10).
// Each thread still owns whole sites (reads all 20 in-channels before writing).
__global__ __launch_bounds__(256) void k_final(const float* __restrict__ u2,
                                               const float* __restrict__ Wxy,
                                               const float* __restrict__ cw,
                                               const float* __restrict__ cb,
                                               float* __restrict__ h) {
    __shared__ __align__(16) float su2[CC * NKY * NZ * 2];  // 51.2 KB
    int bid = blockIdx.x;                 // ((b*128)+x)*2 + half
    int half = bid & 1;
    int x = (bid >> 1) & 127;
    int b = bid >> 8;
    for (int i = threadIdx.x; i < CC * NKY * NZ * 2; i += 256) {
        int o = i / (NKY * NZ * 2), r = i % (NKY * NZ * 2);
        su2[i] = u2[((size_t)(b * CC + o) * NX + x) * (NKY * NZ * 2) + r];
    }
    __syncthreads();
    for (int k = 0; k < 5; k++) {
        int sid = threadIdx.x + 256 * k + 1280 * half;
        int y = sid / NZ, z = sid % NZ;
        float cy[NKY], sy[NKY];
#pragma unroll
        for (int kyi = 0; kyi < NKY; kyi++) {
            float2 w = *(const float2*)&Wxy[(y * NKX + kyi) * 2]; // L1-cached, 16 KB table
            cy[kyi] = w.x; sy[kyi] = w.y;
        }
        size_t hbase = (size_t)b * CC * CH_STRIDE + (size_t)x * (NY * NZ) + (size_t)(y * NZ + z);
        float hv[CC];
#pragma unroll
        for (int i = 0; i < CC; i++) hv[i] = h[hbase + (size_t)i * CH_STRIDE];
        for (int o = 0; o < CC; o++) {
            float acc = cb[o];
#pragma unroll
            for (int i = 0; i < CC; i++) acc = fmaf(cw[o * CC + i], hv[i], acc);
            const float* up = &su2[o * (NKY * NZ * 2) + z * 2];
            float sup = 0.f;
#pragma unroll
            for (int kyi = 0; kyi < NKY; kyi++) {
                float2 u = *(const float2*)&up[kyi * (NZ * 2)];
                // Re{(ur+i*ui) * e^{+i th}} with table = e^{-i th}=(c,s): = ur*c + ui*s
                sup = fmaf(u.x, cy[kyi], sup);
                sup = fmaf(u.y, sy[kyi], sup);
            }
            float v = acc + sup;
            h[hbase + (size_t)o * CH_STRIDE] = v > 0.f ? v : 0.f;
        }
    }
}

// head: out[b,x,y,t] = fc2(relu(fc1(h[b,:,x,y,t])))
// R12: 4 sites per thread — the 640 uniform ds_read_b128/site drop to 160/site;
// per-site FMA order identical to R5 kernel -> bitwise-same result.
__global__ __launch_bounds__(256) void k_head(const float* __restrict__ h,
                                              const float* __restrict__ w1,
                                              const float* __restrict__ b1,
                                              const float* __restrict__ w2,
                                              const float* __restrict__ b2,
                                              float* __restrict__ out) {
    __shared__ __align__(16) float sw1[CC * 128];   // 10 KB
    __shared__ __align__(16) float sb1[128];
    __shared__ __align__(16) float sw2[128];
    for (int i = threadIdx.x; i < CC * 128; i += 256) sw1[i] = w1[i];
    if (threadIdx.x < 128) {
        sb1[threadIdx.x] = b1[threadIdx.x];
        sw2[threadIdx.x] = w2[threadIdx.x];
    }
    __syncthreads();
    int base = blockIdx.x * 1024 + threadIdx.x;       // sites: base + 256*s, s=0..3
    float hv[4][CC];
    size_t ob[4];
#pragma unroll
    for (int s = 0; s < 4; s++) {
        int tid = base + 256 * s;                     // ((b*NX+x)*NY+y)*NZ+t
        int t = tid % NZ;
        int r = tid / NZ;
        int y = r & 127; r >>= 7;
        int x = r & 127;
        int b = r >> 7;
        size_t hbase = (size_t)b * CC * CH_STRIDE + (size_t)x * (NY * NZ) + (size_t)(y * NZ + t);
        ob[s] = (size_t)tid;
#pragma unroll
        for (int c = 0; c < CC; c++) hv[s][c] = h[hbase + (size_t)c * CH_STRIDE];
    }
    float acc0 = b2[0], acc1 = b2[0], acc2 = b2[0], acc3 = b2[0];
    for (int jc = 0; jc < 32; jc++) {
        const float4 sb = *(const float4*)&sb1[jc * 4];
        float4 s0 = sb, s1 = sb, s2 = sb, s3 = sb;
#pragma unroll
        for (int c = 0; c < CC; c++) {
            const float4 w = *(const float4*)&sw1[c * 128 + jc * 4];  // uniform -> LDS broadcast
            s0.x = fmaf(hv[0][c], w.x, s0.x); s0.y = fmaf(hv[0][c], w.y, s0.y);
            s0.z = fmaf(hv[0][c], w.z, s0.z); s0.w = fmaf(hv[0][c], w.w, s0.w);
            s1.x = fmaf(hv[1][c], w.x, s1.x); s1.y = fmaf(hv[1][c], w.y, s1.y);
            s1.z = fmaf(hv[1][c], w.z, s1.z); s1.w = fmaf(hv[1][c], w.w, s1.w);
            s2.x = fmaf(hv[2][c], w.x, s2.x); s2.y = fmaf(hv[2][c], w.y, s2.y);
            s2.z = fmaf(hv[2][c], w.z, s2.z); s2.w = fmaf(hv[2][c], w.w, s2.w);
            s3.x = fmaf(hv[3][c], w.x, s3.x); s3.y = fmaf(hv[3][c], w.y, s3.y);
            s3.z = fmaf(hv[3][c], w.z, s3.z); s3.w = fmaf(hv[3][c], w.w, s3.w);
        }
        const float4 v2 = *(const float4*)&sw2[jc * 4];
        acc0 = fmaf(fmaxf(s0.x, 0.f), v2.x, acc0); acc0 = fmaf(fmaxf(s0.y, 0.f), v2.y, acc0);
        acc0 = fmaf(fmaxf(s0.z, 0.f), v2.z, acc0); acc0 = fmaf(fmaxf(s0.w, 0.f), v2.w, acc0);
        acc1 = fmaf(fmaxf(s1.x, 0.f), v2.x, acc1); acc1 = fmaf(fmaxf(s1.y, 0.f), v2.y, acc1);
        acc1 = fmaf(fmaxf(s1.z, 0.f), v2.z, acc1); acc1 = fmaf(fmaxf(s1.w, 0.f), v2.w, acc1);
        acc2 = fmaf(fmaxf(s2.x, 0.f), v2.x, acc2); acc2 = fmaf(fmaxf(s2.y, 0.f), v2.y, acc2);
        acc2 = fmaf(fmaxf(s2.z, 0.f), v2.z, acc2); acc2 = fmaf(fmaxf(s2.w, 0.f), v2.w, acc2);
        acc3 = fmaf(fmaxf(s3.x, 0.f), v2.x, acc3); acc3 = fmaf(fmaxf(s3.y, 0.f), v2.y, acc3);
        acc3 = fmaf(fmaxf(s3.z, 0.f), v2.z, acc3); acc3 = fmaf(fmaxf(s3.w, 0.f), v2.w, acc3);
    }
    out[ob[0]] = acc0;
    out[ob[1]] = acc1;
    out[ob[2]] = acc2;
    out[ob[3]] = acc3;
}

extern "C" void kernel_launch(void* const* d_in, const int* in_sizes, int n_in,
                              void* d_out, int out_size, void* d_ws, size_t ws_size,
                              hipStream_t stream) {
    const float* x       = (const float*)d_in[0];
    const float* spec_wr = (const float*)d_in[1];
    const float* spec_wi = (const float*)d_in[2];
    const float* conv_w  = (const float*)d_in[3];
    const float* conv_b  = (const float*)d_in[4];
    const float* fc0_w   = (const float*)d_in[5];
    const float* fc0_b   = (const float*)d_in[6];
    const float* fc1_w   = (const float*)d_in[7];
    const float* fc1_b   = (const float*)d_in[8];
    const float* fc2_w   = (const float*)d_in[9];
    const float* fc2_b   = (const float*)d_in[10];

    float* ws   = (float*)d_ws;
    float* h    = ws + OFF_H;
    float* t1   = ws + OFF_T1;
    float* t2   = ws + OFF_T2;
    float* A    = ws + OFF_A;
    float* Aout = ws + OFF_AOUT;
    float* Wxy  = ws + OFF_WXY;
    float* Wz   = ws + OFF_WZ;

    hipLaunchKernelGGL(k_tables, dim3(9), dim3(256), 0, stream, Wxy, Wz);
    hipLaunchKernelGGL(k_fc0, dim3(5120), dim3(256), 0, stream, x, fc0_w, fc0_b, h);
    for (int l = 0; l < 4; l++) {
        hipLaunchKernelGGL(k_dft_y, dim3(2560), dim3(320), 0, stream, h, Wxy, t1);
        hipLaunchKernelGGL(k_dft_x, dim3(1280), dim3(320), 0, stream, t1, Wxy, t2);
        hipLaunchKernelGGL(k_dft_z, dim3(640), dim3(256), 0, stream, t2, Wz, A);
        hipLaunchKernelGGL(k_modemix, dim3(640), dim3(256), 0, stream, A, spec_wr, spec_wi, Aout, l);
        hipLaunchKernelGGL(k_invz, dim3(1600), dim3(256), 0, stream, Aout, Wz, t2);
        hipLaunchKernelGGL(k_invx, dim3(12800), dim3(256), 0, stream, t2, Wxy, t1);
        hipLaunchKernelGGL(k_final, dim3(1024), dim3(256), 0, stream, t1, Wxy,
                           conv_w + l * (CC * CC), conv_b + l * CC, h);
    }
    hipLaunchKernelGGL(k_head, dim3(1280), dim3(256), 0, stream,
                       h, fc1_w, fc1_b, fc2_w, fc2_b, (float*)d_out);
}

// Round 16
// 1012.134 us; speedup vs baseline: 1.2891x; 1.1737x over previous
//
#include <hip/hip_runtime.h>

// FNO2DTime on gfx950 — partial-DFT spectral conv, fp32 throughout.
//
// Key derivation (matches numpy/pocketfft irfftn semantics):
//   out[x,y,z] = (1/N) * Re{ sum_{kx,ky in K, kz in 0..7} c(kz) * Aout * e^{+i phi} }
//   c(0)=1 (c2r ignores Im of DC bin), c(kz>=1)=2 (Hermitian partner),
//   N = 128*128*20. Re taken once at the final (Y) inverse stage.
//
// R5:  k_head weights staged in LDS (228 -> 124 us; VALUBusy 43->84%).
// R12: k_head 4 sites/thread (124 -> <116 us). k_final y-half split REGRESSED
//      (+12 us/launch, staging dup) — reverted in R15.
// R15: k_final y-pairing: Wxy[y+64][k] = (-1)^k Wxy[y][k], so sites (y,z) and
//      (y+64,z) share su2 reads via even/odd partial sums. Was LDS-instr bound:
//      16 waves/CU x 1600 ds_read_b64 x ~8cyc ~= 85us + 25us conflicts ~= 117us
//      measured. Halves LDS reads AND spectral FMAs per site; 512 blocks again.

#define BB 4
#define CC 20
#define NX 128
#define NY 128
#define NZ 20
#define MM 8
#define NKX 16
#define NKY 16
#define NKZ 8
#define CH_STRIDE (NX * NY * NZ) /* 327680 */

// workspace offsets in floats
#define OFF_H    0u
#define OFF_T1   26214400u  /* [bc][x][kyi][z] cplx ; reused as u2 [bo][x][kyi][z] */
#define OFF_T2   32768000u  /* [bc][kxi][kyi][z] cplx ; reused as u1 */
#define OFF_A    33587200u  /* [b][i][kxi][kyi][kz] cplx */
#define OFF_AOUT 33914880u  /* [b][o][kxi][kyi][kz] cplx */
#define OFF_WXY  34242560u  /* [y][ki] cplx, e^{-2pi i y*kphys/128} */
#define OFF_WZ   34246656u  /* [z][kz] cplx, e^{-2pi i z*kz/20} */
// total 34,246,976 floats ~= 137 MB

__global__ void k_tables(float* __restrict__ Wxy, float* __restrict__ Wz) {
    int tid = blockIdx.x * blockDim.x + threadIdx.x;
    const double PI2 = 6.283185307179586476925286766559;
    if (tid < NX * NKX) {
        int y = tid >> 4, ki = tid & 15;
        int kphys = (ki < MM) ? ki : (NX - NKX + ki);   // 8..15 -> 120..127
        int p = (y * kphys) & (NX - 1);
        double ang = -PI2 * (double)p / (double)NX;
        Wxy[2 * tid]     = (float)cos(ang);
        Wxy[2 * tid + 1] = (float)sin(ang);
    } else if (tid < NX * NKX + NZ * NKZ) {
        int t = tid - NX * NKX;
        int z = t >> 3, kz = t & 7;
        int p = (z * kz) % NZ;
        double ang = -PI2 * (double)p / (double)NZ;
        Wz[2 * t]     = (float)cos(ang);
        Wz[2 * t + 1] = (float)sin(ang);
    }
}

// fc0 lift: h[b,c,x,y,t] = b0[c] + gx*w0[0,c] + gy*w0[1,c] + gt[t]*w0[2,c] + sum_k x[b,x,y,k]*w0[3+k,c]
__global__ __launch_bounds__(256) void k_fc0(const float* __restrict__ x,
                                             const float* __restrict__ w0,
                                             const float* __restrict__ b0,
                                             float* __restrict__ h) {
    int tid = blockIdx.x * blockDim.x + threadIdx.x;      // ((b*CC+c)*NX+xx)*NY+y
    if (tid >= BB * CC * NX * NY) return;
    int y = tid & 127;
    int r = tid >> 7;
    int xx = r & 127; r >>= 7;
    int c = r % CC;
    int b = r / CC;
    const float* xp = x + (((size_t)(b * NX + xx)) * NY + y) * NZ;
    float base = b0[c] + ((float)xx / 127.0f) * w0[0 * CC + c]
                       + ((float)y  / 127.0f) * w0[1 * CC + c];
#pragma unroll
    for (int k = 0; k < 20; k++) base = fmaf(xp[k], w0[(3 + k) * CC + c], base);
    float wt = w0[2 * CC + c];
    float* hp = h + (size_t)tid * NZ;
#pragma unroll
    for (int t = 0; t < 20; t++) hp[t] = base + ((float)(t + 1) / 20.0f) * wt;
}

// Y-DFT: t1[bc][x][kyi][z] = sum_y h[bc][x][y][z] * Wxy[y][kyi]
// block = (bc, xgroup of 4), 320 threads: (xl in 4) x (ki in 16) x (z0 in {0,4,8,12,16})
__global__ __launch_bounds__(320) void k_dft_y(const float* __restrict__ h,
                                               const float* __restrict__ Wxy,
                                               float* __restrict__ t1) {
    __shared__ __align__(16) float tile[4 * NY * NZ];   // 40 KB
    __shared__ __align__(16) float tw[NX * NKX * 2];    // 16 KB
    int bid = blockIdx.x;                // (b*CC+c)*32 + xg
    int bc = bid >> 5, xg = bid & 31;
    const float* hp = h + ((size_t)bc * NX + xg * 4) * (NY * NZ);
    for (int i = threadIdx.x; i < 4 * NY * NZ; i += 320) tile[i] = hp[i];
    for (int i = threadIdx.x; i < NX * NKX * 2; i += 320) tw[i] = Wxy[i];
    __syncthreads();
    int xl = threadIdx.x / 80;
    int rest = threadIdx.x % 80;
    int ki = rest / 5;
    int z0 = (rest % 5) * 4;
    const float* tp = tile + xl * (NY * NZ);
    float sr0 = 0, sr1 = 0, sr2 = 0, sr3 = 0, si0 = 0, si1 = 0, si2 = 0, si3 = 0;
    for (int y = 0; y < NY; y++) {
        const float4 v = *(const float4*)&tp[y * NZ + z0];
        const float2 w = *(const float2*)&tw[(y * NKX + ki) * 2];
        sr0 = fmaf(v.x, w.x, sr0); si0 = fmaf(v.x, w.y, si0);
        sr1 = fmaf(v.y, w.x, sr1); si1 = fmaf(v.y, w.y, si1);
        sr2 = fmaf(v.z, w.x, sr2); si2 = fmaf(v.z, w.y, si2);
        sr3 = fmaf(v.w, w.x, sr3); si3 = fmaf(v.w, w.y, si3);
    }
    int x = xg * 4 + xl;
    float* o = t1 + (((size_t)bc * NX + x) * NKY + ki) * (NZ * 2) + z0 * 2;
    float4 o0 = {sr0, si0, sr1, si1};
    float4 o1 = {sr2, si2, sr3, si3};
    *(float4*)&o[0] = o0;
    *(float4*)&o[4] = o1;
}

// X-DFT: t2[bc][kxi][kyi][z] = sum_x t1[bc][x][kyi][z] * Wxy[x][kxi]
// block = (bc, kyi), 320 threads: (ki in 16) x (z in 20)
__global__ __launch_bounds__(320) void k_dft_x(const float* __restrict__ t1,
                                               const float* __restrict__ Wxy,
                                               float* __restrict__ t2) {
    __shared__ __align__(16) float tile[NX * NZ * 2];   // 20.5 KB
    __shared__ __align__(16) float tw[NX * NKX * 2];    // 16 KB
    int bid = blockIdx.x;
    int bc = bid >> 4, kyi = bid & 15;
    const float* base = t1 + ((size_t)bc * NX * NKY * NZ + (size_t)kyi * NZ) * 2;
    for (int i = threadIdx.x; i < NX * NZ * 2; i += 320) {
        int xx = i / (NZ * 2), r2 = i % (NZ * 2);
        tile[i] = base[(size_t)xx * (NKY * NZ * 2) + r2];
    }
    for (int i = threadIdx.x; i < NX * NKX * 2; i += 320) tw[i] = Wxy[i];
    __syncthreads();
    int ki = threadIdx.x / NZ, z = threadIdx.x % NZ;
    float sr = 0.f, si = 0.f;
    for (int xx = 0; xx < NX; xx++) {
        const float2 a = *(const float2*)&tile[xx * (NZ * 2) + z * 2];
        const float2 w = *(const float2*)&tw[(xx * NKX + ki) * 2];
        sr += a.x * w.x - a.y * w.y;
        si += a.x * w.y + a.y * w.x;
    }
    float* o = t2 + ((((size_t)bc * NKX + ki) * NKY + kyi) * NZ + z) * 2;
    o[0] = sr; o[1] = si;
}

// Z-DFT: A[b][i][kxi][kyi][kz] = sum_z t2[..][z] * Wz[z][kz]
__global__ __launch_bounds__(256) void k_dft_z(const float* __restrict__ t2,
                                               const float* __restrict__ Wz,
                                               float* __restrict__ A) {
    int tid = blockIdx.x * blockDim.x + threadIdx.x;  // ((bc*16+kxi)*16+kyi)*8+kz
    if (tid >= BB * CC * NKX * NKY * NKZ) return;
    int kz = tid & 7;
    int rest = tid >> 3;
    const float* p = t2 + (size_t)rest * (NZ * 2);
    float sr = 0.f, si = 0.f;
#pragma unroll
    for (int z = 0; z < NZ; z++) {
        float2 a = *(const float2*)&p[2 * z];
        float2 w = *(const float2*)&Wz[(z * NKZ + kz) * 2];
        sr += a.x * w.x - a.y * w.y;
        si += a.x * w.y + a.y * w.x;
    }
    A[2 * tid] = sr; A[2 * tid + 1] = si;
}

// mode mix: Aout[b][o][m] = scale * sum_i A[b][i][m] * (wr + i wi)[l,q,i,o,mx,my,mz]
__global__ __launch_bounds__(256) void k_modemix(const float* __restrict__ A,
                                                 const float* __restrict__ wr,
                                                 const float* __restrict__ wi,
                                                 float* __restrict__ Aout, int layer) {
    int tid = blockIdx.x * blockDim.x + threadIdx.x;  // (((b*CC+o)*16+kxi)*16+kyi)*8+kz
    if (tid >= BB * CC * NKX * NKY * NKZ) return;
    int kz = tid & 7;
    int t = tid >> 3;
    int kyi = t & 15; t >>= 4;
    int kxi = t & 15; t >>= 4;
    int o = t % CC;
    int b = t / CC;
    int q = (kxi >= MM ? 1 : 0) + (kyi >= MM ? 2 : 0);
    int mx = kxi & 7, my = kyi & 7;
    size_t wbase = ((size_t)(layer * 4 + q) * (CC * CC) + o) * 512
                 + (size_t)(mx * 64 + my * 8 + kz);
    const float* Ab = A + ((size_t)b * CC * 2048 + (size_t)((kxi * NKY + kyi) * NKZ + kz)) * 2;
    float sr = 0.f, si = 0.f;
#pragma unroll
    for (int i = 0; i < CC; i++) {
        float ar = Ab[(size_t)i * 4096], ai = Ab[(size_t)i * 4096 + 1];
        float wrv = wr[wbase + (size_t)i * (CC * 512)];
        float wiv = wi[wbase + (size_t)i * (CC * 512)];
        sr += ar * wrv - ai * wiv;
        si += ar * wiv + ai * wrv;
    }
    float sc = (kz == 0 ? 1.0f : 2.0f) / 327680.0f;   // c(kz) / N
    Aout[2 * tid] = sr * sc; Aout[2 * tid + 1] = si * sc;
}

// inverse Z: u1[b][o][kxi][kyi][z] = sum_kz Aout * conj(Wz[z][kz])
__global__ __launch_bounds__(256) void k_invz(const float* __restrict__ Aout,
                                              const float* __restrict__ Wz,
                                              float* __restrict__ u1) {
    int tid = blockIdx.x * blockDim.x + threadIdx.x;  // rest*20+z
    if (tid >= BB * CC * NKX * NKY * NZ) return;
    int z = tid % NZ;
    int rest = tid / NZ;
    const float* p = Aout + (size_t)rest * (NKZ * 2);
    float sr = 0.f, si = 0.f;
#pragma unroll
    for (int kz = 0; kz < NKZ; kz++) {
        float2 a = *(const float2*)&p[2 * kz];
        float c = Wz[(z * NKZ + kz) * 2], s = -Wz[(z * NKZ + kz) * 2 + 1];
        sr += a.x * c - a.y * s;
        si += a.x * s + a.y * c;
    }
    u1[2 * tid] = sr; u1[2 * tid + 1] = si;
}

// inverse X: u2[bo][x][kyi][z] = sum_kxi u1[bo][kxi][kyi][z] * conj(Wxy[x][kxi])
__global__ __launch_bounds__(256) void k_invx(const float* __restrict__ u1,
                                              const float* __restrict__ Wxy,
                                              float* __restrict__ u2) {
    int tid = blockIdx.x * blockDim.x + threadIdx.x;  // ((bo*NX+x)*NKY+kyi)*NZ+z
    if (tid >= BB * CC * NX * NKY * NZ) return;
    int z = tid % NZ;
    int t = tid / NZ;
    int kyi = t & 15; t >>= 4;
    int x = t & 127;
    int bo = t >> 7;
    const float* p = u1 + ((size_t)bo * (NKX * NKY * NZ) + (size_t)(kyi * NZ + z)) * 2;
    float sr = 0.f, si = 0.f;
#pragma unroll
    for (int kxi = 0; kxi < NKX; kxi++) {
        float2 a = *(const float2*)&p[(size_t)kxi * (NKY * NZ * 2)];
        float c = Wxy[(x * NKX + kxi) * 2], s = -Wxy[(x * NKX + kxi) * 2 + 1];
        sr += a.x * c - a.y * s;
        si += a.x * s + a.y * c;
    }
    u2[2 * tid] = sr; u2[2 * tid + 1] = si;
}

// inverse Y + pointwise conv + bias + relu, IN PLACE on h.
// R15: y-pairing — thread handles sites (y,z) and (y+64,z). Since
// Wxy[y+64][kyi] = (-1)^kyi * Wxy[y][kyi], the two sites share all su2 reads:
// accumulate even/odd-kyi partials (se,so); sup_a = se+so, sup_b = se-so.
// Halves ds_read_b64 count AND spectral FMAs per site. 512 blocks (one per
// (b,x)), su2 staged with float4. Thread reads all 40 hv values before any
// write -> no in-place hazard (sites disjoint across threads).
__global__ __launch_bounds__(256) void k_final(const float* __restrict__ u2,
                                               const float* __restrict__ Wxy,
                                               const float* __restrict__ cw,
                                               const float* __restrict__ cb,
                                               float* __restrict__ h) {
    __shared__ __align__(16) float su2[CC * NKY * NZ * 2];  // 51.2 KB
    int b = blockIdx.x >> 7, x = blockIdx.x & 127;
    for (int i4 = threadIdx.x; i4 < (CC * NKY * NZ * 2) / 4; i4 += 256) {
        int o = i4 / 160, r4 = i4 % 160;
        *(float4*)&su2[o * 640 + r4 * 4] =
            *(const float4*)&u2[((size_t)(b * CC + o) * NX + x) * 640 + r4 * 4];
    }
    __syncthreads();
    for (int k = 0; k < 5; k++) {
        int p = threadIdx.x + 256 * k;      // 0..1279 = (y in 0..63) x (z in 0..19)
        int z = p % NZ;
        int y = p / NZ;
        float cy[NKY], sy[NKY];
#pragma unroll
        for (int kyi = 0; kyi < NKY; kyi++) {
            float2 w = *(const float2*)&Wxy[(y * NKX + kyi) * 2]; // L1-cached
            cy[kyi] = w.x; sy[kyi] = w.y;
        }
        size_t hbase_a = (size_t)b * CC * CH_STRIDE + (size_t)x * (NY * NZ) + (size_t)(y * NZ + z);
        size_t hbase_b = hbase_a + (size_t)(64 * NZ);
        float hva[CC], hvb[CC];
#pragma unroll
        for (int i = 0; i < CC; i++) {
            hva[i] = h[hbase_a + (size_t)i * CH_STRIDE];
            hvb[i] = h[hbase_b + (size_t)i * CH_STRIDE];
        }
        for (int o = 0; o < CC; o++) {
            float acca = cb[o], accb = cb[o];
#pragma unroll
            for (int i = 0; i < CC; i++) {
                float w = cw[o * CC + i];
                acca = fmaf(w, hva[i], acca);
                accb = fmaf(w, hvb[i], accb);
            }
            const float* up = &su2[o * (NKY * NZ * 2) + z * 2];
            float se = 0.f, so = 0.f;
#pragma unroll
            for (int kk = 0; kk < 8; kk++) {
                // Re{(ur+i*ui) * e^{+i th}} with table = e^{-i th}=(c,s): ur*c + ui*s
                float2 ue = *(const float2*)&up[(2 * kk) * (NZ * 2)];
                se = fmaf(ue.x, cy[2 * kk], se);
                se = fmaf(ue.y, sy[2 * kk], se);
                float2 uo = *(const float2*)&up[(2 * kk + 1) * (NZ * 2)];
                so = fmaf(uo.x, cy[2 * kk + 1], so);
                so = fmaf(uo.y, sy[2 * kk + 1], so);
            }
            float va = acca + (se + so);
            float vb = accb + (se - so);
            h[hbase_a + (size_t)o * CH_STRIDE] = va > 0.f ? va : 0.f;
            h[hbase_b + (size_t)o * CH_STRIDE] = vb > 0.f ? vb : 0.f;
        }
    }
}

// head: out[b,x,y,t] = fc2(relu(fc1(h[b,:,x,y,t])))
// R12: 4 sites per thread — the 640 uniform ds_read_b128/site drop to 160/site;
// per-site FMA order identical to R5 kernel -> bitwise-same result.
__global__ __launch_bounds__(256) void k_head(const float* __restrict__ h,
                                              const float* __restrict__ w1,
                                              const float* __restrict__ b1,
                                              const float* __restrict__ w2,
                                              const float* __restrict__ b2,
                                              float* __restrict__ out) {
    __shared__ __align__(16) float sw1[CC * 128];   // 10 KB
    __shared__ __align__(16) float sb1[128];
    __shared__ __align__(16) float sw2[128];
    for (int i = threadIdx.x; i < CC * 128; i += 256) sw1[i] = w1[i];
    if (threadIdx.x < 128) {
        sb1[threadIdx.x] = b1[threadIdx.x];
        sw2[threadIdx.x] = w2[threadIdx.x];
    }
    __syncthreads();
    int base = blockIdx.x * 1024 + threadIdx.x;       // sites: base + 256*s, s=0..3
    float hv[4][CC];
    size_t ob[4];
#pragma unroll
    for (int s = 0; s < 4; s++) {
        int tid = base + 256 * s;                     // ((b*NX+x)*NY+y)*NZ+t
        int t = tid % NZ;
        int r = tid / NZ;
        int y = r & 127; r >>= 7;
        int x = r & 127;
        int b = r >> 7;
        size_t hbase = (size_t)b * CC * CH_STRIDE + (size_t)x * (NY * NZ) + (size_t)(y * NZ + t);
        ob[s] = (size_t)tid;
#pragma unroll
        for (int c = 0; c < CC; c++) hv[s][c] = h[hbase + (size_t)c * CH_STRIDE];
    }
    float acc0 = b2[0], acc1 = b2[0], acc2 = b2[0], acc3 = b2[0];
    for (int jc = 0; jc < 32; jc++) {
        const float4 sb = *(const float4*)&sb1[jc * 4];
        float4 s0 = sb, s1 = sb, s2 = sb, s3 = sb;
#pragma unroll
        for (int c = 0; c < CC; c++) {
            const float4 w = *(const float4*)&sw1[c * 128 + jc * 4];  // uniform -> LDS broadcast
            s0.x = fmaf(hv[0][c], w.x, s0.x); s0.y = fmaf(hv[0][c], w.y, s0.y);
            s0.z = fmaf(hv[0][c], w.z, s0.z); s0.w = fmaf(hv[0][c], w.w, s0.w);
            s1.x = fmaf(hv[1][c], w.x, s1.x); s1.y = fmaf(hv[1][c], w.y, s1.y);
            s1.z = fmaf(hv[1][c], w.z, s1.z); s1.w = fmaf(hv[1][c], w.w, s1.w);
            s2.x = fmaf(hv[2][c], w.x, s2.x); s2.y = fmaf(hv[2][c], w.y, s2.y);
            s2.z = fmaf(hv[2][c], w.z, s2.z); s2.w = fmaf(hv[2][c], w.w, s2.w);
            s3.x = fmaf(hv[3][c], w.x, s3.x); s3.y = fmaf(hv[3][c], w.y, s3.y);
            s3.z = fmaf(hv[3][c], w.z, s3.z); s3.w = fmaf(hv[3][c], w.w, s3.w);
        }
        const float4 v2 = *(const float4*)&sw2[jc * 4];
        acc0 = fmaf(fmaxf(s0.x, 0.f), v2.x, acc0); acc0 = fmaf(fmaxf(s0.y, 0.f), v2.y, acc0);
        acc0 = fmaf(fmaxf(s0.z, 0.f), v2.z, acc0); acc0 = fmaf(fmaxf(s0.w, 0.f), v2.w, acc0);
        acc1 = fmaf(fmaxf(s1.x, 0.f), v2.x, acc1); acc1 = fmaf(fmaxf(s1.y, 0.f), v2.y, acc1);
        acc1 = fmaf(fmaxf(s1.z, 0.f), v2.z, acc1); acc1 = fmaf(fmaxf(s1.w, 0.f), v2.w, acc1);
        acc2 = fmaf(fmaxf(s2.x, 0.f), v2.x, acc2); acc2 = fmaf(fmaxf(s2.y, 0.f), v2.y, acc2);
        acc2 = fmaf(fmaxf(s2.z, 0.f), v2.z, acc2); acc2 = fmaf(fmaxf(s2.w, 0.f), v2.w, acc2);
        acc3 = fmaf(fmaxf(s3.x, 0.f), v2.x, acc3); acc3 = fmaf(fmaxf(s3.y, 0.f), v2.y, acc3);
        acc3 = fmaf(fmaxf(s3.z, 0.f), v2.z, acc3); acc3 = fmaf(fmaxf(s3.w, 0.f), v2.w, acc3);
    }
    out[ob[0]] = acc0;
    out[ob[1]] = acc1;
    out[ob[2]] = acc2;
    out[ob[3]] = acc3;
}

extern "C" void kernel_launch(void* const* d_in, const int* in_sizes, int n_in,
                              void* d_out, int out_size, void* d_ws, size_t ws_size,
                              hipStream_t stream) {
    const float* x       = (const float*)d_in[0];
    const float* spec_wr = (const float*)d_in[1];
    const float* spec_wi = (const float*)d_in[2];
    const float* conv_w  = (const float*)d_in[3];
    const float* conv_b  = (const float*)d_in[4];
    const float* fc0_w   = (const float*)d_in[5];
    const float* fc0_b   = (const float*)d_in[6];
    const float* fc1_w   = (const float*)d_in[7];
    const float* fc1_b   = (const float*)d_in[8];
    const float* fc2_w   = (const float*)d_in[9];
    const float* fc2_b   = (const float*)d_in[10];

    float* ws   = (float*)d_ws;
    float* h    = ws + OFF_H;
    float* t1   = ws + OFF_T1;
    float* t2   = ws + OFF_T2;
    float* A    = ws + OFF_A;
    float* Aout = ws + OFF_AOUT;
    float* Wxy  = ws + OFF_WXY;
    float* Wz   = ws + OFF_WZ;

    hipLaunchKernelGGL(k_tables, dim3(9), dim3(256), 0, stream, Wxy, Wz);
    hipLaunchKernelGGL(k_fc0, dim3(5120), dim3(256), 0, stream, x, fc0_w, fc0_b, h);
    for (int l = 0; l < 4; l++) {
        hipLaunchKernelGGL(k_dft_y, dim3(2560), dim3(320), 0, stream, h, Wxy, t1);
        hipLaunchKernelGGL(k_dft_x, dim3(1280), dim3(320), 0, stream, t1, Wxy, t2);
        hipLaunchKernelGGL(k_dft_z, dim3(640), dim3(256), 0, stream, t2, Wz, A);
        hipLaunchKernelGGL(k_modemix, dim3(640), dim3(256), 0, stream, A, spec_wr, spec_wi, Aout, l);
        hipLaunchKernelGGL(k_invz, dim3(1600), dim3(256), 0, stream, Aout, Wz, t2);
        hipLaunchKernelGGL(k_invx, dim3(12800), dim3(256), 0, stream, t2, Wxy, t1);
        hipLaunchKernelGGL(k_final, dim3(512), dim3(256), 0, stream, t1, Wxy,
                           conv_w + l * (CC * CC), conv_b + l * CC, h);
    }
    hipLaunchKernelGGL(k_head, dim3(1280), dim3(256), 0, stream,
                       h, fc1_w, fc1_b, fc2_w, fc2_b, (float*)d_out);
}